// Round 1
// baseline (1513.869 us; speedup 1.0000x reference)
//
#include <hip/hip_runtime.h>
#include <hip/hip_bf16.h>

#define N_NODES 100000
#define N_EDGES 3200000
#define IN_CH 128
#define HID 16
#define OUT_CH 64

// ---------------- degree / norm ----------------
__global__ void k_deg_init(float* __restrict__ deg, int n) {
    int i = blockIdx.x * blockDim.x + threadIdx.x;
    if (i < n) deg[i] = 1.0f;  // self-loop contributes 1 to every node's degree
}

__global__ void k_deg_edges(const int* __restrict__ dst, float* __restrict__ deg, int e) {
    int i = blockIdx.x * blockDim.x + threadIdx.x;
    if (i < e) atomicAdd(&deg[dst[i]], 1.0f);
}

__global__ void k_rsqrt(float* __restrict__ deg, int n) {
    int i = blockIdx.x * blockDim.x + threadIdx.x;
    if (i < n) deg[i] = rsqrtf(deg[i]);  // deg >= 1 always (self-loop)
}

// ---------------- layer-1 transform: h1 = x @ W1  (N x 128) @ (128 x 16) ----------------
__global__ __launch_bounds__(256) void k_gemm1(const float* __restrict__ x,
                                               const float* __restrict__ W1,
                                               float* __restrict__ h1, int n) {
    __shared__ float Ws[IN_CH * HID];     // 2048 f
    __shared__ float xs[16][IN_CH + 1];   // 16 rows, padded stride
    int tid = threadIdx.x;
    for (int i = tid; i < IN_CH * HID; i += 256) Ws[i] = W1[i];
    int row0 = blockIdx.x * 16;
    for (int i = tid; i < 16 * IN_CH; i += 256) {
        int r = i / IN_CH, c = i % IN_CH;
        int row = row0 + r;
        xs[r][c] = (row < n) ? x[(size_t)row * IN_CH + c] : 0.f;
    }
    __syncthreads();
    int r = tid >> 4, c = tid & 15;  // 16 rows x 16 cols
    float acc = 0.f;
#pragma unroll
    for (int k = 0; k < IN_CH; ++k) acc = fmaf(xs[r][k], Ws[k * HID + c], acc);
    int row = row0 + r;
    if (row < n) h1[(size_t)row * HID + c] = acc;
}

// ---------------- edge scatter: agg[dst] += h[src] * dinv[src]*dinv[dst]  (16 ch) ----------------
__global__ void k_agg16(const int* __restrict__ src, const int* __restrict__ dst,
                        const float* __restrict__ dinv, const float* __restrict__ h,
                        float* __restrict__ agg, int e) {
    int gid = blockIdx.x * blockDim.x + threadIdx.x;
    int eid = gid >> 2, q = gid & 3;
    if (eid >= e) return;
    int s = src[eid], d = dst[eid];
    float w = dinv[s] * dinv[d];
    const float4 v = *reinterpret_cast<const float4*>(&h[(size_t)s * HID + q * 4]);
    float* a = &agg[(size_t)d * HID + q * 4];
    atomicAdd(a + 0, v.x * w);
    atomicAdd(a + 1, v.y * w);
    atomicAdd(a + 2, v.z * w);
    atomicAdd(a + 3, v.w * w);
}

// ---------------- h2 = relu(agg1 + h1*dinv^2 + b1)   (in-place over h1 is safe) ----------------
__global__ void k_bias_relu(const float* __restrict__ agg1, const float* __restrict__ h1,
                            const float* __restrict__ dinv, const float* __restrict__ b1,
                            float* __restrict__ h2, int n) {
    int gid = blockIdx.x * blockDim.x + threadIdx.x;
    if (gid >= n * HID) return;
    int i = gid >> 4, c = gid & 15;
    float w = dinv[i];
    float v = agg1[gid] + h1[gid] * w * w + b1[c];
    h2[gid] = fmaxf(v, 0.f);
}

// ---------------- out = (agg2 + h2*dinv^2) @ W2 + b2   (N x 16) @ (16 x 64) ----------------
__global__ __launch_bounds__(256) void k_out(const float* __restrict__ agg2,
                                             const float* __restrict__ h2,
                                             const float* __restrict__ dinv,
                                             const float* __restrict__ W2,
                                             const float* __restrict__ b2,
                                             float* __restrict__ out, int n) {
    __shared__ float Ws[HID * OUT_CH];  // 1024 f
    __shared__ float as[4][HID];
    int tid = threadIdx.x;
    for (int i = tid; i < HID * OUT_CH; i += 256) Ws[i] = W2[i];
    int row0 = blockIdx.x * 4;
    if (tid < 4 * HID) {
        int r = tid / HID, c = tid % HID;
        int row = row0 + r;
        if (row < n) {
            float w = dinv[row];
            as[r][c] = agg2[(size_t)row * HID + c] + h2[(size_t)row * HID + c] * w * w;
        } else {
            as[r][c] = 0.f;
        }
    }
    __syncthreads();
    int r = tid >> 6, c = tid & 63;  // 4 rows x 64 cols
    float acc = b2[c];
#pragma unroll
    for (int k = 0; k < HID; ++k) acc = fmaf(as[r][k], Ws[k * OUT_CH + c], acc);
    int row = row0 + r;
    if (row < n) out[(size_t)row * OUT_CH + c] = acc;
}

extern "C" void kernel_launch(void* const* d_in, const int* in_sizes, int n_in,
                              void* d_out, int out_size, void* d_ws, size_t ws_size,
                              hipStream_t stream) {
    const float* x  = (const float*)d_in[0];
    const int*   ei = (const int*)d_in[1];
    const float* W1 = (const float*)d_in[2];
    const float* b1 = (const float*)d_in[3];
    const float* W2 = (const float*)d_in[4];
    const float* b2 = (const float*)d_in[5];
    float* out = (float*)d_out;

    const int* src = ei;            // edge_index[0]
    const int* dst = ei + N_EDGES;  // edge_index[1]

    float* ws   = (float*)d_ws;
    float* dinv = ws;                        // N floats
    float* h    = ws + 100352;               // N*16 floats (h1, then h2 in-place)
    float* agg  = ws + 100352 + 1600256;     // N*16 floats (agg1, reused as agg2)

    const int B = 256;

    k_deg_init<<<(N_NODES + B - 1) / B, B, 0, stream>>>(dinv, N_NODES);
    k_deg_edges<<<(N_EDGES + B - 1) / B, B, 0, stream>>>(dst, dinv, N_EDGES);
    k_rsqrt<<<(N_NODES + B - 1) / B, B, 0, stream>>>(dinv, N_NODES);

    k_gemm1<<<(N_NODES + 15) / 16, B, 0, stream>>>(x, W1, h, N_NODES);

    hipMemsetAsync(agg, 0, (size_t)N_NODES * HID * sizeof(float), stream);
    k_agg16<<<((size_t)4 * N_EDGES + B - 1) / B, B, 0, stream>>>(src, dst, dinv, h, agg, N_EDGES);

    k_bias_relu<<<(N_NODES * HID + B - 1) / B, B, 0, stream>>>(agg, h, dinv, b1, h, N_NODES);

    hipMemsetAsync(agg, 0, (size_t)N_NODES * HID * sizeof(float), stream);
    k_agg16<<<((size_t)4 * N_EDGES + B - 1) / B, B, 0, stream>>>(src, dst, dinv, h, agg, N_EDGES);

    k_out<<<(N_NODES + 3) / 4, B, 0, stream>>>(agg, h, dinv, W2, b2, out, N_NODES);
}

// Round 2
// 528.999 us; speedup vs baseline: 2.8618x; 2.8618x over previous
//
#include <hip/hip_runtime.h>
#include <hip/hip_bf16.h>

#define N_NODES 100000
#define N_EDGES 3200000
#define IN_CH 128
#define HID 16
#define OUT_CH 64

// ---------------- degree histogram (int atomics) ----------------
__global__ void k_deg_edges(const int* __restrict__ dst, int* __restrict__ degi, int e) {
    int i = blockIdx.x * blockDim.x + threadIdx.x;
    if (i < e) atomicAdd(&degi[dst[i]], 1);
}

__global__ void k_rsqrt(const int* __restrict__ degi, float* __restrict__ dinv, int n) {
    int i = blockIdx.x * blockDim.x + threadIdx.x;
    if (i < n) dinv[i] = rsqrtf((float)degi[i] + 1.0f);  // +1 self-loop
}

// ---------------- exclusive prefix scan of degi -> row_ptr ----------------
__global__ __launch_bounds__(256) void k_scan1(const int* __restrict__ in, int* __restrict__ outEx,
                                               int* __restrict__ sums, int n) {
    __shared__ int sh[256];
    int b = blockIdx.x, t = threadIdx.x;
    int base = b * 1024 + t * 4;
    int v0 = (base + 0 < n) ? in[base + 0] : 0;
    int v1 = (base + 1 < n) ? in[base + 1] : 0;
    int v2 = (base + 2 < n) ? in[base + 2] : 0;
    int v3 = (base + 3 < n) ? in[base + 3] : 0;
    int tsum = v0 + v1 + v2 + v3;
    sh[t] = tsum;
    __syncthreads();
    for (int off = 1; off < 256; off <<= 1) {
        int x = (t >= off) ? sh[t - off] : 0;
        __syncthreads();
        sh[t] += x;
        __syncthreads();
    }
    int excl = sh[t] - tsum;
    if (t == 255) sums[b] = sh[255];
    if (base + 0 < n) outEx[base + 0] = excl;
    if (base + 1 < n) outEx[base + 1] = excl + v0;
    if (base + 2 < n) outEx[base + 2] = excl + v0 + v1;
    if (base + 3 < n) outEx[base + 3] = excl + v0 + v1 + v2;
}

__global__ __launch_bounds__(256) void k_scan2(int* __restrict__ sums, int nb) {
    __shared__ int sh[256];
    int t = threadIdx.x;
    int v = (t < nb) ? sums[t] : 0;
    sh[t] = v;
    __syncthreads();
    for (int off = 1; off < 256; off <<= 1) {
        int x = (t >= off) ? sh[t - off] : 0;
        __syncthreads();
        sh[t] += x;
        __syncthreads();
    }
    if (t < nb) sums[t] = sh[t] - v;  // exclusive
}

__global__ void k_scan3(int* __restrict__ outEx, const int* __restrict__ sums, int n) {
    int i = blockIdx.x * blockDim.x + threadIdx.x;
    if (i < n) outEx[i] += sums[i >> 10];
}

// ---------------- CSR fill: col[row_ptr[d] + pos] = src ----------------
__global__ void k_fill(const int* __restrict__ src, const int* __restrict__ dst,
                       const int* __restrict__ row_ptr, int* __restrict__ fill,
                       int* __restrict__ col, int e) {
    int i = blockIdx.x * blockDim.x + threadIdx.x;
    if (i >= e) return;
    int d = dst[i];
    int p = atomicAdd(&fill[d], 1);
    col[row_ptr[d] + p] = src[i];
}

// ---------------- layer-1 transform: h1 = x @ W1  (N x 128) @ (128 x 16) ----------------
__global__ __launch_bounds__(256) void k_gemm1(const float* __restrict__ x,
                                               const float* __restrict__ W1,
                                               float* __restrict__ h1, int n) {
    __shared__ float Ws[IN_CH * HID];
    __shared__ float xs[16][IN_CH + 1];
    int tid = threadIdx.x;
    for (int i = tid; i < IN_CH * HID; i += 256) Ws[i] = W1[i];
    int row0 = blockIdx.x * 16;
    for (int i = tid; i < 16 * IN_CH; i += 256) {
        int r = i / IN_CH, c = i % IN_CH;
        int row = row0 + r;
        xs[r][c] = (row < n) ? x[(size_t)row * IN_CH + c] : 0.f;
    }
    __syncthreads();
    int r = tid >> 4, c = tid & 15;
    float acc = 0.f;
#pragma unroll
    for (int k = 0; k < IN_CH; ++k) acc = fmaf(xs[r][k], Ws[k * HID + c], acc);
    int row = row0 + r;
    if (row < n) h1[(size_t)row * HID + c] = acc;
}

// ---------------- gather layer 1: h2 = relu(sum_e w*h1[s] + dinv^2*h1[i] + b1) ----------------
__global__ void k_gather1(const float* __restrict__ h1, const int* __restrict__ row_ptr,
                          const int* __restrict__ cnt, const float* __restrict__ dinv,
                          const int* __restrict__ col, const float* __restrict__ b1,
                          float* __restrict__ h2, int n) {
    int t = blockIdx.x * blockDim.x + threadIdx.x;
    int i = t >> 2, q = t & 3;
    if (i >= n) return;
    float di = dinv[i];
    float4 hv = *reinterpret_cast<const float4*>(&h1[(size_t)i * HID + q * 4]);
    float4 acc;
    float dii = di * di;
    acc.x = hv.x * dii; acc.y = hv.y * dii; acc.z = hv.z * dii; acc.w = hv.w * dii;
    int j0 = row_ptr[i], j1 = j0 + cnt[i];
    for (int j = j0; j < j1; ++j) {
        int s = col[j];
        float w = dinv[s] * di;
        float4 v = *reinterpret_cast<const float4*>(&h1[(size_t)s * HID + q * 4]);
        acc.x = fmaf(v.x, w, acc.x);
        acc.y = fmaf(v.y, w, acc.y);
        acc.z = fmaf(v.z, w, acc.z);
        acc.w = fmaf(v.w, w, acc.w);
    }
    float4 b = *reinterpret_cast<const float4*>(&b1[q * 4]);
    acc.x = fmaxf(acc.x + b.x, 0.f);
    acc.y = fmaxf(acc.y + b.y, 0.f);
    acc.z = fmaxf(acc.z + b.z, 0.f);
    acc.w = fmaxf(acc.w + b.w, 0.f);
    *reinterpret_cast<float4*>(&h2[(size_t)i * HID + q * 4]) = acc;
}

// ---------------- gather layer 2 fused with (N x 16)@(16 x 64) + b2 ----------------
__global__ __launch_bounds__(256) void k_gather2_out(const float* __restrict__ h2,
                                                     const int* __restrict__ row_ptr,
                                                     const int* __restrict__ cnt,
                                                     const float* __restrict__ dinv,
                                                     const int* __restrict__ col,
                                                     const float* __restrict__ W2,
                                                     const float* __restrict__ b2,
                                                     float* __restrict__ out, int n) {
    __shared__ float Ws[HID * OUT_CH];   // 1024 f
    __shared__ float as[64][HID + 1];    // padded
    int t = threadIdx.x;
    for (int i = t; i < HID * OUT_CH; i += 256) Ws[i] = W2[i];
    int i0 = blockIdx.x * 64;
    int nl = t >> 2, q = t & 3;
    int i = i0 + nl;
    if (i < n) {
        float di = dinv[i];
        float dii = di * di;
        float4 hv = *reinterpret_cast<const float4*>(&h2[(size_t)i * HID + q * 4]);
        float4 acc;
        acc.x = hv.x * dii; acc.y = hv.y * dii; acc.z = hv.z * dii; acc.w = hv.w * dii;
        int j0 = row_ptr[i], j1 = j0 + cnt[i];
        for (int j = j0; j < j1; ++j) {
            int s = col[j];
            float w = dinv[s] * di;
            float4 v = *reinterpret_cast<const float4*>(&h2[(size_t)s * HID + q * 4]);
            acc.x = fmaf(v.x, w, acc.x);
            acc.y = fmaf(v.y, w, acc.y);
            acc.z = fmaf(v.z, w, acc.z);
            acc.w = fmaf(v.w, w, acc.w);
        }
        as[nl][q * 4 + 0] = acc.x;
        as[nl][q * 4 + 1] = acc.y;
        as[nl][q * 4 + 2] = acc.z;
        as[nl][q * 4 + 3] = acc.w;
    } else {
        as[nl][q * 4 + 0] = 0.f;
        as[nl][q * 4 + 1] = 0.f;
        as[nl][q * 4 + 2] = 0.f;
        as[nl][q * 4 + 3] = 0.f;
    }
    __syncthreads();
    int g = q;  // col group: cols g*16 .. g*16+15
    float r[16];
#pragma unroll
    for (int c = 0; c < 16; ++c) r[c] = b2[g * 16 + c];
#pragma unroll
    for (int k = 0; k < HID; ++k) {
        float a = as[nl][k];
#pragma unroll
        for (int c = 0; c < 16; ++c) r[c] = fmaf(a, Ws[k * OUT_CH + g * 16 + c], r[c]);
    }
    if (i < n) {
        float4* o = reinterpret_cast<float4*>(&out[(size_t)i * OUT_CH + g * 16]);
        o[0] = make_float4(r[0], r[1], r[2], r[3]);
        o[1] = make_float4(r[4], r[5], r[6], r[7]);
        o[2] = make_float4(r[8], r[9], r[10], r[11]);
        o[3] = make_float4(r[12], r[13], r[14], r[15]);
    }
}

extern "C" void kernel_launch(void* const* d_in, const int* in_sizes, int n_in,
                              void* d_out, int out_size, void* d_ws, size_t ws_size,
                              hipStream_t stream) {
    const float* x  = (const float*)d_in[0];
    const int*   ei = (const int*)d_in[1];
    const float* W1 = (const float*)d_in[2];
    const float* b1 = (const float*)d_in[3];
    const float* W2 = (const float*)d_in[4];
    const float* b2 = (const float*)d_in[5];
    float* out = (float*)d_out;

    const int* src = ei;
    const int* dst = ei + N_EDGES;

    // workspace layout (4B elements)
    int*   degi    = (int*)d_ws;                    // [0 .. 100000)     degree, then reused as fill counter
    int*   row_ptr = (int*)d_ws + 100000;           // [100000 .. 200000)
    float* dinv    = (float*)d_ws + 200000;         // [200000 .. 300000)
    int*   sums    = (int*)d_ws + 300000;           // [300000 .. 300256)
    int*   col     = (int*)d_ws + 300256;           // [300256 .. 3500256)
    float* h       = (float*)d_ws + 3500256;        // [3500256 .. 5100256)  h1
    float* h2      = (float*)d_ws + 5100256;        // [5100256 .. 6700256)  post-relu layer-1 out

    const int B = 256;
    const int nb_scan = (N_NODES + 1023) / 1024;  // 98

    // degree histogram
    hipMemsetAsync(degi, 0, (size_t)N_NODES * sizeof(int), stream);
    k_deg_edges<<<(N_EDGES + B - 1) / B, B, 0, stream>>>(dst, degi, N_EDGES);

    // row_ptr = exclusive scan(degi)
    k_scan1<<<nb_scan, B, 0, stream>>>(degi, row_ptr, sums, N_NODES);
    k_scan2<<<1, B, 0, stream>>>(sums, nb_scan);
    k_scan3<<<(N_NODES + B - 1) / B, B, 0, stream>>>(row_ptr, sums, N_NODES);

    // dinv = rsqrt(deg+1)
    k_rsqrt<<<(N_NODES + B - 1) / B, B, 0, stream>>>(degi, dinv, N_NODES);

    // h1 = x @ W1 (independent of CSR build)
    k_gemm1<<<(N_NODES + 15) / 16, B, 0, stream>>>(x, W1, h, N_NODES);

    // CSR fill (degi reused as per-node fill cursor; ends equal to degree again)
    hipMemsetAsync(degi, 0, (size_t)N_NODES * sizeof(int), stream);
    k_fill<<<(N_EDGES + B - 1) / B, B, 0, stream>>>(src, dst, row_ptr, degi, col, N_EDGES);

    // layer 1 aggregation + bias + relu
    k_gather1<<<((size_t)4 * N_NODES + B - 1) / B, B, 0, stream>>>(h, row_ptr, degi, dinv, col, b1,
                                                                   h2, N_NODES);

    // layer 2 aggregation fused with final GEMM + bias
    k_gather2_out<<<(N_NODES + 63) / 64, B, 0, stream>>>(h2, row_ptr, degi, dinv, col, W2, b2, out,
                                                         N_NODES);
}